// Round 5
// baseline (1350.868 us; speedup 1.0000x reference)
//
#include <hip/hip_runtime.h>

#define NN 50000
#define NE 1000000
#define NG 1000
#define KE 147
#define DH 128

using u16 = unsigned short;
typedef __attribute__((ext_vector_type(8))) short bf16x8;
typedef __attribute__((ext_vector_type(4))) float f32x4;

__device__ __forceinline__ float lrelu(float v){ return fmaxf(v, 0.01f*v); }
__device__ __forceinline__ float bf2f(u16 u){ unsigned int x = ((unsigned int)u)<<16; float f; __builtin_memcpy(&f,&x,4); return f; }
__device__ __forceinline__ u16 f2bf(float f){ unsigned int x; __builtin_memcpy(&x,&f,4); x += 0x7fffu + ((x>>16)&1u); return (u16)(x>>16); }
// column permutation: memory position p holds logical column pi(p)
__device__ __host__ __forceinline__ int cpi(int p){ return (p & 64) | ((p & 3) << 4) | ((p & 63) >> 2); }

// ================= CSR build =================
__global__ __launch_bounds__(256) void hist_kernel(const int* __restrict__ endi, const int* __restrict__ srt,
                                                   int* __restrict__ cntE, int* __restrict__ cntS){
  for (int i = blockIdx.x*256 + threadIdx.x; i < NE; i += gridDim.x*256){
    atomicAdd(&cntE[endi[i]], 1);
    atomicAdd(&cntS[srt[i]], 1);
  }
}

__global__ __launch_bounds__(1024) void scan2_kernel(const int* __restrict__ cntE, int* __restrict__ offE,
                                                     const int* __restrict__ cntS, int* __restrict__ offS){
  const int* deg = blockIdx.x ? cntS : cntE;
  int* off = blockIdx.x ? offS : offE;
  __shared__ int wsum[17];
  const int t = threadIdx.x, lane = t & 63, wv = t >> 6;
  int carry = 0;
  for (int base = 0; base < 50176; base += 1024){
    const int i = base + t;
    int v = (i < NN) ? deg[i] : 0;
    int s = v;
    #pragma unroll
    for (int d = 1; d < 64; d <<= 1){
      int x = __shfl_up(s, d);
      if (lane >= d) s += x;
    }
    if (lane == 63) wsum[wv] = s;
    __syncthreads();
    if (t == 0){
      int run = 0;
      #pragma unroll
      for (int k = 0; k < 16; ++k){ int x = wsum[k]; wsum[k] = run; run += x; }
      wsum[16] = run;
    }
    __syncthreads();
    if (i <= NN) off[i] = carry + wsum[wv] + s - v;
    carry += wsum[16];
    __syncthreads();
  }
}

__global__ __launch_bounds__(256) void scatter_kernel(const int* __restrict__ endi, const int* __restrict__ srt,
                                                      int* __restrict__ curE, int* __restrict__ curS,
                                                      int* __restrict__ rankE, int* __restrict__ srtE,
                                                      int* __restrict__ listS, int* __restrict__ endS){
  for (int i = blockIdx.x*256 + threadIdx.x; i < NE; i += gridDim.x*256){
    const int e = endi[i], s = srt[i];
    int p = atomicAdd(&curE[e], 1);
    rankE[i] = p; srtE[p] = s;
    int q = atomicAdd(&curS[s], 1);
    listS[q] = i; endS[q] = e;
  }
}

__global__ __launch_bounds__(256) void post_kernel(const int* __restrict__ listS, const int* __restrict__ rankE,
                                                   int* __restrict__ listS2){
  for (int i = blockIdx.x*256 + threadIdx.x; i < NE; i += gridDim.x*256)
    listS2[i] = rankE[listS[i]];
}

// Wb0: natural layout padded K=160. Wb1: K permuted by cpi. bp0/bp1: biases permuted by cpi.
__global__ __launch_bounds__(256) void convertW_kernel(const float* __restrict__ W1, const float* __restrict__ W0,
                                                       const float* __restrict__ b0, const float* __restrict__ b1,
                                                       u16* __restrict__ Wb1, u16* __restrict__ Wb0,
                                                       float* __restrict__ bp0, float* __restrict__ bp1){
  int i = blockIdx.x*256 + threadIdx.x;
  if (i < 128*128){
    int j = i >> 7, k = i & 127;
    Wb1[i] = f2bf(W1[j*DH + cpi(k)]);
  }
  if (i < 128*160){
    int j = i/160, k = i - j*160;
    Wb0[i] = (k < KE) ? f2bf(W0[j*KE + k]) : (u16)0;
  }
  if (i < 128){ bp0[i] = b0[cpi(i)]; bp1[i] = b1[cpi(i)]; }
}

// ================= layer 0: h'[rankE[e]] = lrelu(cf[e] @ W0^T + b)  — NO LDS, pi-order stores =====
__global__ __launch_bounds__(256) void layer0_mfma(const float* __restrict__ cf, const u16* __restrict__ Wb0,
                                                   const float* __restrict__ bp0, const int* __restrict__ rankE,
                                                   u16* __restrict__ h){
  const int t = threadIdx.x, lane = t & 63, wv = t >> 6;
  const int wr = wv >> 1, wc = wv & 1;
  const long e0 = (long)blockIdx.x * 128;
  const int q = lane & 15, kg8 = (lane >> 4) * 8;

  bf16x8 bfrag[5][4];
  #pragma unroll
  for (int fc = 0; fc < 4; ++fc)
    #pragma unroll
    for (int ks = 0; ks < 5; ++ks)
      bfrag[ks][fc] = *(const bf16x8*)&Wb0[(size_t)(wc*64 + fc*16 + q)*160 + ks*32 + kg8];

  f32x4 acc[4][4];
  #pragma unroll
  for (int fr = 0; fr < 4; ++fr)
    #pragma unroll
    for (int fc = 0; fc < 4; ++fc){ acc[fr][fc][0]=0.f; acc[fr][fc][1]=0.f; acc[fr][fc][2]=0.f; acc[fr][fc][3]=0.f; }

  #pragma unroll
  for (int ks = 0; ks < 5; ++ks){
    bf16x8 a[4];
    #pragma unroll
    for (int fr = 0; fr < 4; ++fr){
      const long e = e0 + wr*64 + fr*16 + q;
      const float* rp = cf + (size_t)e*KE;
      bf16x8 av;
      #pragma unroll
      for (int j = 0; j < 8; ++j){
        const int kk = ks*32 + kg8 + j;
        float v = 0.f;
        if (e < (long)NE && (ks < 4 || kk < KE)) v = rp[kk];   // ks<4 folds to true
        av[j] = (short)f2bf(v);
      }
      a[fr] = av;
    }
    #pragma unroll
    for (int fr = 0; fr < 4; ++fr)
      #pragma unroll
      for (int fc = 0; fc < 4; ++fc)
        acc[fr][fc] = __builtin_amdgcn_mfma_f32_16x16x32_bf16(a[fr], bfrag[ks][fc], acc[fr][fc], 0, 0, 0);
  }

  const float4 bb = *(const float4*)&bp0[wc*64 + q*4];
  #pragma unroll
  for (int fr = 0; fr < 4; ++fr){
    #pragma unroll
    for (int r = 0; r < 4; ++r){
      const long ee = e0 + wr*64 + fr*16 + (lane>>4)*4 + r;
      if (ee < (long)NE){
        const int row = rankE[ee];
        ushort4 o;
        o.x = f2bf(lrelu(acc[fr][0][r] + bb.x));
        o.y = f2bf(lrelu(acc[fr][1][r] + bb.y));
        o.z = f2bf(lrelu(acc[fr][2][r] + bb.z));
        o.w = f2bf(lrelu(acc[fr][3][r] + bb.w));
        *(ushort4*)&h[(size_t)row*DH + wc*64 + q*4] = o;
      }
    }
  }
}

// ================= agg[n] = sum of h' rows [offE[n], offE[n+1]) — sequential =================
__global__ __launch_bounds__(256) void aggE_kernel(const u16* __restrict__ h, const int* __restrict__ off,
                                                   float* __restrict__ agg){
  const int t = threadIdx.x, lane = t & 63, wv = t >> 6;
  const int n = blockIdx.x*4 + wv;
  if (n >= NN) return;
  const int lo = off[n], hi = off[n+1];
  const int c4 = (lane & 31)*4, sub = lane >> 5;
  float a0=0.f, a1=0.f, a2=0.f, a3=0.f;
  for (int i = lo + sub; i < hi; i += 2){
    ushort4 hv = *(const ushort4*)&h[(size_t)i*DH + c4];
    a0 += bf2f(hv.x); a1 += bf2f(hv.y); a2 += bf2f(hv.z); a3 += bf2f(hv.w);
  }
  a0 += __shfl_xor(a0, 32); a1 += __shfl_xor(a1, 32);
  a2 += __shfl_xor(a2, 32); a3 += __shfl_xor(a3, 32);
  if (sub == 0) *(float4*)&agg[(size_t)n*DH + c4] = make_float4(a0,a1,a2,a3);
}

// ================= P/Q GEMM: P = agg@W^T + b ; Q = h'[rankE[0:N]]@W^T  (pi-order in and out) =====
__global__ __launch_bounds__(256) void pq_gemm(const float* __restrict__ agg, const u16* __restrict__ h,
                                               const int* __restrict__ rankE, const u16* __restrict__ Wb1,
                                               const float* __restrict__ bp1, float* __restrict__ P,
                                               float* __restrict__ Q){
  __shared__ u16 Alds[128][136];
  const int t = threadIdx.x, lane = t & 63, wv = t >> 6;
  const int wr = wv >> 1, wc = wv & 1;
  const int r0 = blockIdx.x * 128;
  const int q = lane & 15, kg8 = (lane >> 4)*8;

  bf16x8 bfrag[4][4];
  #pragma unroll
  for (int fc = 0; fc < 4; ++fc)
    #pragma unroll
    for (int ks = 0; ks < 4; ++ks)
      bfrag[ks][fc] = *(const bf16x8*)&Wb1[(size_t)(wc*64 + fc*16 + q)*128 + ks*32 + kg8];

  {
    const int rt = t >> 1, half = t & 1;
    const int gr = r0 + rt;
    u16* dst = &Alds[rt][half*64];
    if (gr < NN){
      const float4* src = (const float4*)&agg[(size_t)gr*DH + half*64];
      #pragma unroll
      for (int p = 0; p < 16; ++p){
        float4 x = src[p];
        ushort4 o; o.x=f2bf(x.x); o.y=f2bf(x.y); o.z=f2bf(x.z); o.w=f2bf(x.w);
        *(ushort4*)&dst[p*4] = o;
      }
    } else if (gr < 2*NN){
      const int row = rankE[gr - NN];
      const ushort4* src = (const ushort4*)&h[(size_t)row*DH + half*64];
      #pragma unroll
      for (int p = 0; p < 16; ++p) *(ushort4*)&dst[p*4] = src[p];
    } else {
      ushort4 z; z.x=0; z.y=0; z.z=0; z.w=0;
      #pragma unroll
      for (int p = 0; p < 16; ++p) *(ushort4*)&dst[p*4] = z;
    }
  }
  __syncthreads();

  f32x4 acc[4][4];
  #pragma unroll
  for (int fr = 0; fr < 4; ++fr)
    #pragma unroll
    for (int fc = 0; fc < 4; ++fc){ acc[fr][fc][0]=0.f; acc[fr][fc][1]=0.f; acc[fr][fc][2]=0.f; acc[fr][fc][3]=0.f; }
  #pragma unroll
  for (int ks = 0; ks < 4; ++ks){
    bf16x8 a[4];
    #pragma unroll
    for (int fr = 0; fr < 4; ++fr)
      a[fr] = *(const bf16x8*)&Alds[wr*64 + fr*16 + q][ks*32 + kg8];
    #pragma unroll
    for (int fr = 0; fr < 4; ++fr)
      #pragma unroll
      for (int fc = 0; fc < 4; ++fc)
        acc[fr][fc] = __builtin_amdgcn_mfma_f32_16x16x32_bf16(a[fr], bfrag[ks][fc], acc[fr][fc], 0, 0, 0);
  }

  const float4 bb = *(const float4*)&bp1[wc*64 + q*4];
  #pragma unroll
  for (int fr = 0; fr < 4; ++fr){
    #pragma unroll
    for (int r = 0; r < 4; ++r){
      const int grow = r0 + wr*64 + fr*16 + (lane>>4)*4 + r;
      if (grow < NN){
        float4 val = make_float4(acc[fr][0][r] + bb.x, acc[fr][1][r] + bb.y,
                                 acc[fr][2][r] + bb.z, acc[fr][3][r] + bb.w);
        *(float4*)&P[(size_t)grow*DH + wc*64 + q*4] = val;
      } else if (grow < 2*NN){
        float4 val = make_float4(acc[fr][0][r], acc[fr][1][r], acc[fr][2][r], acc[fr][3][r]);
        *(float4*)&Q[(size_t)(grow-NN)*DH + wc*64 + q*4] = val;
      }
    }
  }
}

// ===== middle layers: h'[i] = lrelu(h'[i] + P[srtE[i]] - Q[n]); agg[n]=sum =====
__global__ __launch_bounds__(256) void fused_mid(u16* __restrict__ h, const float* __restrict__ P,
                                                 const float* __restrict__ Q, const int* __restrict__ srtE,
                                                 const int* __restrict__ off, float* __restrict__ agg){
  const int t = threadIdx.x, lane = t & 63, wv = t >> 6;
  const int n = blockIdx.x*4 + wv;
  if (n >= NN) return;
  const int lo = off[n], hi = off[n+1];
  const int c4 = (lane & 31)*4, sub = lane >> 5;
  const float4 qv = *(const float4*)&Q[(size_t)n*DH + c4];
  float a0=0.f, a1=0.f, a2=0.f, a3=0.f;
  for (int i = lo + sub; i < hi; i += 2){
    const int s = srtE[i];
    ushort4 hv = *(const ushort4*)&h[(size_t)i*DH + c4];
    float4 pv = *(const float4*)&P[(size_t)s*DH + c4];
    float v0 = lrelu(bf2f(hv.x) + pv.x - qv.x);
    float v1 = lrelu(bf2f(hv.y) + pv.y - qv.y);
    float v2 = lrelu(bf2f(hv.z) + pv.z - qv.z);
    float v3 = lrelu(bf2f(hv.w) + pv.w - qv.w);
    ushort4 o; o.x=f2bf(v0); o.y=f2bf(v1); o.z=f2bf(v2); o.w=f2bf(v3);
    *(ushort4*)&h[(size_t)i*DH + c4] = o;
    a0 += v0; a1 += v1; a2 += v2; a3 += v3;
  }
  a0 += __shfl_xor(a0, 32); a1 += __shfl_xor(a1, 32);
  a2 += __shfl_xor(a2, 32); a3 += __shfl_xor(a3, 32);
  if (sub == 0) *(float4*)&agg[(size_t)n*DH + c4] = make_float4(a0,a1,a2,a3);
}

// ===== last layer: hnode[s] = sum over srt-CSR of lrelu(h'[listS2[i]] + P[s] - Q[endS[i]]) =====
__global__ __launch_bounds__(256) void fused_last(const u16* __restrict__ h, const float* __restrict__ P,
                                                  const float* __restrict__ Q, const int* __restrict__ endS,
                                                  const int* __restrict__ listS2, const int* __restrict__ off,
                                                  float* __restrict__ hnode){
  const int t = threadIdx.x, lane = t & 63, wv = t >> 6;
  const int s = blockIdx.x*4 + wv;
  if (s >= NN) return;
  const int lo = off[s], hi = off[s+1];
  const int c4 = (lane & 31)*4, sub = lane >> 5;
  const float4 pv = *(const float4*)&P[(size_t)s*DH + c4];
  float a0=0.f, a1=0.f, a2=0.f, a3=0.f;
  for (int i = lo + sub; i < hi; i += 2){
    const int row = listS2[i];
    const int d = endS[i];
    ushort4 hv = *(const ushort4*)&h[(size_t)row*DH + c4];
    float4 qv = *(const float4*)&Q[(size_t)d*DH + c4];
    a0 += lrelu(bf2f(hv.x) + pv.x - qv.x);
    a1 += lrelu(bf2f(hv.y) + pv.y - qv.y);
    a2 += lrelu(bf2f(hv.z) + pv.z - qv.z);
    a3 += lrelu(bf2f(hv.w) + pv.w - qv.w);
  }
  a0 += __shfl_xor(a0, 32); a1 += __shfl_xor(a1, 32);
  a2 += __shfl_xor(a2, 32); a3 += __shfl_xor(a3, 32);
  if (sub == 0) *(float4*)&hnode[(size_t)s*DH + c4] = make_float4(a0,a1,a2,a3);
}

// ================= nodes: atom = lrelu(hnode @ Wmol^T + b); normed = atom/||atom|| =================
// hnode columns are pi-permuted; permute Wmol's K during staging. Outputs canonical.
__global__ __launch_bounds__(256) void node_kernel(
    const float* __restrict__ hn, const float* __restrict__ W,
    const float* __restrict__ b, float* __restrict__ atom, float* __restrict__ normed)
{
  __shared__ float Wt[64*132];
  __shared__ float ms[32*DH];
  const int t = threadIdx.x;
  const int r0 = blockIdx.x * 32;
  const int jg = t & 31, eg = t >> 5;
  for (int idx = t; idx < 32*DH; idx += 256) {
    const int r = r0 + (idx >> 7);
    ms[idx] = (r < NN) ? hn[(size_t)r*DH + (idx & 127)] : 0.f;
  }
  float acc[4][4] = {};
  for (int c = 0; c < 2; ++c) {
    __syncthreads();
    for (int idx = t; idx < 128*64; idx += 256) {
      const int j = idx >> 6, kl = idx & 63;
      Wt[kl*132 + j] = W[j*DH + c*64 + ((kl&3)*16 + (kl>>2))];   // pi64 on K
    }
    __syncthreads();
    #pragma unroll 4
    for (int kl = 0; kl < 64; ++kl) {
      const float4 w = *(const float4*)&Wt[kl*132 + jg*4];
      const int kg = c*64 + kl;
      #pragma unroll
      for (int i = 0; i < 4; ++i) {
        const float mv = ms[(eg*4+i)*DH + kg];
        acc[i][0] += mv*w.x; acc[i][1] += mv*w.y; acc[i][2] += mv*w.z; acc[i][3] += mv*w.w;
      }
    }
  }
  float bj[4];
  #pragma unroll
  for (int c2 = 0; c2 < 4; ++c2) bj[c2] = b[jg*4 + c2];
  #pragma unroll
  for (int i = 0; i < 4; ++i) {
    const int r = r0 + eg*4 + i;
    float v[4]; float ss = 0.f;
    #pragma unroll
    for (int c2 = 0; c2 < 4; ++c2) { v[c2] = lrelu(acc[i][c2] + bj[c2]); ss += v[c2]*v[c2]; }
    ss += __shfl_xor(ss, 1); ss += __shfl_xor(ss, 2); ss += __shfl_xor(ss, 4);
    ss += __shfl_xor(ss, 8); ss += __shfl_xor(ss, 16);
    if (r < NN) {
      *(float4*)&atom[(size_t)r*DH + jg*4] = make_float4(v[0],v[1],v[2],v[3]);
      const float inv = 1.f / fmaxf(sqrtf(ss), 1e-12f);
      *(float4*)&normed[(size_t)r*DH + jg*4] = make_float4(v[0]*inv,v[1]*inv,v[2]*inv,v[3]*inv);
    }
  }
}

// ================= per-graph sum + out GEMV =================
__global__ __launch_bounds__(128) void graph_out_kernel(const float* __restrict__ normed, const int* __restrict__ batch,
                                                        const float* __restrict__ Wo, const float* __restrict__ bo,
                                                        float* __restrict__ out){
  const int g = blockIdx.x, t = threadIdx.x;
  int lo, hi;
  { int a=0, bb=NN; while(a<bb){ int m=(a+bb)>>1; if (batch[m] < g) a=m+1; else bb=m; } lo=a; }
  { int a=lo, bb=NN; while(a<bb){ int m=(a+bb)>>1; if (batch[m] < g+1) a=m+1; else bb=m; } hi=a; }
  float s = 0.f;
  for (int n = lo; n < hi; ++n) s += normed[(size_t)n*DH + t];
  float v = s * Wo[t];
  #pragma unroll
  for (int d2 = 1; d2 < 64; d2 <<= 1) v += __shfl_xor(v, d2);
  __shared__ float red[2];
  if ((t & 63) == 0) red[t >> 6] = v;
  __syncthreads();
  if (t == 0) out[g] = red[0] + red[1] + bo[0];
}

extern "C" void kernel_launch(void* const* d_in, const int* in_sizes, int n_in,
                              void* d_out, int out_size, void* d_ws, size_t ws_size,
                              hipStream_t stream)
{
  const float* cf     = (const float*)d_in[1];
  const int*   srt    = (const int*)d_in[2];
  const int*   endi   = (const int*)d_in[3];
  const int*   batch  = (const int*)d_in[5];
  const float* W_init = (const float*)d_in[6];
  const float* b_init = (const float*)d_in[7];
  const float* W_h1   = (const float*)d_in[8];
  const float* b_h1   = (const float*)d_in[9];
  const float* W_mol  = (const float*)d_in[10];
  const float* b_mol  = (const float*)d_in[11];
  const float* W_out  = (const float*)d_in[12];
  const float* b_out  = (const float*)d_in[13];

  float* out  = (float*)d_out;
  float* atom = out + NG;

  char* ws = (char*)d_ws;
  u16*   h      = (u16*)(ws);                    // 256,000,000 B (end-CSR permuted rows, pi cols)
  float* agg    = (float*)(ws + 256000000);      // 25,600,000 B (pi cols)
  float* P      = (float*)(ws + 281600000);      // 25,600,000 B (pi cols)
  float* Q      = (float*)(ws + 307200000);      // 25,600,000 B (pi cols)
  int*   srtE   = (int*)(ws + 332800000);        // 4,000,000 B
  int*   listS  = (int*)(ws + 336800000);        // 4,000,000 B
  int*   endS   = (int*)(ws + 340800000);        // 4,000,000 B
  int*   rankE  = (int*)(ws + 344800000);        // 4,000,000 B
  int*   listS2 = (int*)(ws + 348800000);        // 4,000,000 B
  int*   offE   = (int*)(ws + 352800000);        // 200,704 B
  int*   offS   = (int*)(ws + 353000704);        // 200,704 B
  int*   curE   = (int*)(ws + 353201408);        // 200,704 B
  int*   curS   = (int*)(ws + 353402112);        // 200,704 B
  u16*   Wb1    = (u16*)(ws + 353602816);        // 32,768 B
  u16*   Wb0    = (u16*)(ws + 353635584);        // 40,960 B
  float* bp0    = (float*)(ws + 353676544);      // 512 B
  float* bp1    = (float*)(ws + 353677056);      // 512 B
  float* hnode  = agg;                           // agg dead after last pq_gemm
  float* normed = (float*)(ws);                  // reuse h region (h dead after fused_last)

  // ---- CSR build (int atomics only)
  hipMemsetAsync(curE, 0, 200704, stream);
  hipMemsetAsync(curS, 0, 200704, stream);
  hist_kernel<<<1024, 256, 0, stream>>>(endi, srt, curE, curS);
  scan2_kernel<<<2, 1024, 0, stream>>>(curE, offE, curS, offS);
  hipMemcpyAsync(curE, offE, (size_t)NN*4, hipMemcpyDeviceToDevice, stream);
  hipMemcpyAsync(curS, offS, (size_t)NN*4, hipMemcpyDeviceToDevice, stream);
  scatter_kernel<<<1024, 256, 0, stream>>>(endi, srt, curE, curS, rankE, srtE, listS, endS);
  post_kernel<<<1024, 256, 0, stream>>>(listS, rankE, listS2);
  convertW_kernel<<<80, 256, 0, stream>>>(W_h1, W_init, b_init, b_h1, Wb1, Wb0, bp0, bp1);

  // ---- layer 0 (no LDS; writes h in end-CSR row order, pi col order)
  layer0_mfma<<<(NE + 127)/128, 256, 0, stream>>>(cf, Wb0, bp0, rankE, h);
  aggE_kernel<<<NN/4, 256, 0, stream>>>(h, offE, agg);

  // ---- layers 1..2: tiny P/Q GEMMs + fused sequential update producing next agg
  for (int l = 0; l < 2; ++l){
    pq_gemm<<<(2*NN + 127)/128, 256, 0, stream>>>(agg, h, rankE, Wb1, bp1, P, Q);
    fused_mid<<<NN/4, 256, 0, stream>>>(h, P, Q, srtE, offE, agg);
  }
  // ---- layer 3: P/Q then direct hnode accumulation (no h write, no separate gather)
  pq_gemm<<<(2*NN + 127)/128, 256, 0, stream>>>(agg, h, rankE, Wb1, bp1, P, Q);
  fused_last<<<NN/4, 256, 0, stream>>>(h, P, Q, endS, listS2, offS, hnode);

  // ---- node MLP + normalize, per-graph sum + out
  node_kernel<<<(NN + 31)/32, 256, 0, stream>>>(hnode, W_mol, b_mol, atom, normed);
  graph_out_kernel<<<NG, 128, 0, stream>>>(normed, batch, W_out, b_out, out);
}